// Round 10
// baseline (76.216 us; speedup 1.0000x reference)
//
#include <hip/hip_runtime.h>

#define B 4
#define F 128    // M
#define E 3000   // K
#define T 6000   // N
#define BN 48    // t-columns per block
#define KSTEP 32
#define NKT 94   // ceil(E/32); k 3000..3007 zero-padded
#define NTT 125  // T / BN
#define TDW 50   // dwords per e-pair row (48 + 2 pad): read banks = 8g+lrow -> 2-way max

typedef float f32x4 __attribute__((ext_vector_type(4)));
typedef short bf16x8 __attribute__((ext_vector_type(8)));

static __device__ __forceinline__ unsigned short f32_bf16(float x) {
    unsigned u = __float_as_uint(x);
    u += 0x7FFFu + ((u >> 16) & 1u);
    return (unsigned short)(u >> 16);
}

// ---------------------------------------------------------------------------
// Prologue: pack features into MFMA fragment order (bf16), zero-padded in k.
// Verified R7-R9: lane l of frag (b,kt,ft) holds row m=ft*16+(l&15),
// k = kt*32 + (l>>4)*8 + j.
// ---------------------------------------------------------------------------
__global__ __launch_bounds__(256) void build_afrag(const float* __restrict__ feat,
                                                   unsigned short* __restrict__ afrag) {
    const int gid = blockIdx.x * 256 + threadIdx.x;
    if (gid >= B * NKT * 8 * 64) return;
    const int lane = gid & 63;
    const int frag = gid >> 6;
    const int ft = frag & 7;
    const int kt = (frag >> 3) % NKT;
    const int b  = frag / (8 * NKT);
    const int m  = ft * 16 + (lane & 15);
    const int k0 = kt * 32 + (lane >> 4) * 8;
    const float* src = feat + ((size_t)b * F + m) * E;
    unsigned short v[8];
#pragma unroll
    for (int j = 0; j < 8; ++j) {
        const int k = k0 + j;
        v[j] = (k < E) ? f32_bf16(src[k]) : (unsigned short)0;
    }
    uint4 pack;
    pack.x = (unsigned)v[0] | ((unsigned)v[1] << 16);
    pack.y = (unsigned)v[2] | ((unsigned)v[3] << 16);
    pack.z = (unsigned)v[4] | ((unsigned)v[5] << 16);
    pack.w = (unsigned)v[6] | ((unsigned)v[7] << 16);
    *reinterpret_cast<uint4*>(afrag + (size_t)frag * 512 + lane * 8) = pack;
}

// ---------------------------------------------------------------------------
// Main kernel: wave-split-K, barrier-free main loop (R9-verified structure),
// with conflict-free e-pair LDS layout:
//   element (e,t) <-> dword (e>>1)*TDW + t, half (e&1).
// Writes: ds_write_b64 of 2 packed dwords (bank-uniform). Reads: 4x scalar
// ds_read_b32 per B-frag (2-way max). Dword == MFMA bf16-pair order.
// ---------------------------------------------------------------------------
__global__ __launch_bounds__(256, 2) void unpool_mfma_ws(
        const float* __restrict__ unroll,
        const unsigned short* __restrict__ afrag,
        const float* __restrict__ occ,
        float* __restrict__ out) {
    __shared__ unsigned ut[4][2][16 * TDW];          // 25600 B
    __shared__ f32x4 red[2][3][3][64];               // 18432 B

    // m204 bijective XCD-chunk swizzle: adjacent tb land on the same XCD.
    const int nwg  = NTT * B;                        // 500
    const int orig = blockIdx.x + gridDim.x * blockIdx.y;
    const int q = nwg / 8, r = nwg % 8;              // 62, 4
    const int xcd = orig & 7, lin = orig >> 3;
    const int newid = (xcd < r ? xcd * (q + 1) : r * (q + 1) + (xcd - r) * q) + lin;
    const int tb = newid % NTT;
    const int b  = newid / NTT;
    const int t0 = tb * BN;

    const int tid  = threadIdx.x;
    const int lane = tid & 63;
    const int w    = tid >> 6;    // wave id: owns K-slice
    const int lrow = lane & 15;
    const int g    = lane >> 4;

    const float* ub = unroll + (size_t)b * E * T + t0;
    const unsigned short* ab = afrag + (size_t)b * NKT * 8 * 512;
    unsigned (*myut)[16 * TDW] = ut[w];

    // Staging map: 384 units/step (16 e-pairs x 24 t-pairs), 6 per lane.
    int ep_l[6], t4_l[6];
#pragma unroll
    for (int j = 0; j < 6; ++j) {
        const int u = lane + 64 * j;
        ep_l[j] = u / 24;
        t4_l[j] = (u % 24) * 2;
    }

    // K-slice: waves 0,1 -> 24 steps; waves 2,3 -> 23. (24+24+23+23 = 94)
    const int s0 = w * 23 + (w < 2 ? w : 2);
    const int ns = 23 + (w < 2 ? 1 : 0);
    const int send = s0 + ns;

    f32x4 acc[8][3] = {};

    // Load U rows 2ep, 2ep+1 at t4..t4+1 (both rows share one bounds check:
    // E even, base even -> pairs never straddle).
#define ULOAD(DST, S)                                                                  \
    { _Pragma("unroll") for (int j = 0; j < 6; ++j) {                                  \
          const int e0 = (S) * KSTEP + 2 * ep_l[j];                                    \
          if (e0 < E) {                                                                \
              DST[j][0] = *reinterpret_cast<const float2*>(ub + (size_t)e0 * T + t4_l[j]);        \
              DST[j][1] = *reinterpret_cast<const float2*>(ub + (size_t)(e0 + 1) * T + t4_l[j]);  \
          } else {                                                                     \
              DST[j][0] = make_float2(0.0f, 0.0f);                                     \
              DST[j][1] = make_float2(0.0f, 0.0f);                                     \
          } } }

    // Pack (e even | e odd<<16) per t, vectorized 8B LDS write.
#define UWRITE(SRC, BUF)                                                               \
    { _Pragma("unroll") for (int j = 0; j < 6; ++j) {                                  \
          uint2 d;                                                                     \
          d.x = ((__float_as_uint(SRC[j][0].x) != 0u) ? 0x3F80u : 0u) |                \
                ((__float_as_uint(SRC[j][1].x) != 0u) ? 0x3F800000u : 0u);             \
          d.y = ((__float_as_uint(SRC[j][0].y) != 0u) ? 0x3F80u : 0u) |                \
                ((__float_as_uint(SRC[j][1].y) != 0u) ? 0x3F800000u : 0u);             \
          *reinterpret_cast<uint2*>(&myut[BUF][ep_l[j] * TDW + t4_l[j]]) = d; } }

    // B-frag nt: 4 scalar b32 reads, dword m = elements (8g+2m, 8g+2m+1) at
    // t = nt*16 + lrow -> exactly the bf16x8 k-order.
#define BLOAD(DSTV, BUF, NT)                                                           \
    { union { uint4 u; bf16x8 v; } _bu;                                                \
      _bu.u.x = myut[BUF][(4 * g + 0) * TDW + (NT) * 16 + lrow];                       \
      _bu.u.y = myut[BUF][(4 * g + 1) * TDW + (NT) * 16 + lrow];                       \
      _bu.u.z = myut[BUF][(4 * g + 2) * TDW + (NT) * 16 + lrow];                       \
      _bu.u.w = myut[BUF][(4 * g + 3) * TDW + (NT) * 16 + lrow];                       \
      DSTV = _bu.v; }

#define STEP(S, BUF, UVOLD, UVNEW)                                                     \
    {                                                                                  \
        bf16x8 afr[8];                                                                 \
        const unsigned short* ap = ab + (size_t)(S) * 8 * 512 + lane * 8;              \
        _Pragma("unroll") for (int ft = 0; ft < 8; ++ft)                               \
            afr[ft] = *reinterpret_cast<const bf16x8*>(ap + ft * 512);                 \
        __builtin_amdgcn_sched_barrier(0);                                             \
        if ((S) + 2 < send) ULOAD(UVNEW, (S) + 2);                                     \
        bf16x8 bf0, bf1, bf2;                                                          \
        BLOAD(bf0, BUF, 0); BLOAD(bf1, BUF, 1); BLOAD(bf2, BUF, 2);                    \
        _Pragma("unroll") for (int ft = 0; ft < 8; ++ft) {                             \
            acc[ft][0] = __builtin_amdgcn_mfma_f32_16x16x32_bf16(afr[ft], bf0, acc[ft][0], 0, 0, 0); \
            acc[ft][1] = __builtin_amdgcn_mfma_f32_16x16x32_bf16(afr[ft], bf1, acc[ft][1], 0, 0, 0); \
            acc[ft][2] = __builtin_amdgcn_mfma_f32_16x16x32_bf16(afr[ft], bf2, acc[ft][2], 0, 0, 0); } \
        if ((S) + 1 < send) UWRITE(UVOLD, (BUF) ^ 1);                                  \
    }

    // Prologue: stage step s0 into buf0; issue s0+1 loads.
    float2 uvA[6][2], uvB[6][2];
    ULOAD(uvA, s0);
    UWRITE(uvA, 0);
    if (ns > 1) ULOAD(uvA, s0 + 1);

    for (int i = 0; i < ns; i += 2) {
        STEP(s0 + i, 0, uvA, uvB);
        if (i + 1 < ns) STEP(s0 + i + 1, 1, uvB, uvA);
    }
#undef STEP
#undef BLOAD
#undef UWRITE
#undef ULOAD

    // Epilogue: combine 4 per-wave partials (R9-verified). 4 rounds x 2 chunks.
    float inv[3];
#pragma unroll
    for (int nt = 0; nt < 3; ++nt)
        inv[nt] = 1.0f / occ[b * T + t0 + nt * 16 + lrow];
    float* ob = out + (size_t)b * F * T;

#pragma unroll
    for (int p = 0; p < 4; ++p) {
        __syncthreads();
#pragma unroll
        for (int c = 0; c < 2; ++c) {
            const int ft = 2 * p + c;
            const int fw = 2 * c + (p & 1);     // finalizer wave for this chunk
            if (w != fw) {
                const int slot = (w - fw + 4) % 4 - 1;   // 0..2
#pragma unroll
                for (int nt = 0; nt < 3; ++nt)
                    red[c][slot][nt][lane] = acc[ft][nt];
            }
        }
        __syncthreads();
#pragma unroll
        for (int c = 0; c < 2; ++c) {
            const int ft = 2 * p + c;
            const int fw = 2 * c + (p & 1);
            if (w == fw) {
#pragma unroll
                for (int nt = 0; nt < 3; ++nt) {
                    f32x4 v = acc[ft][nt];
#pragma unroll
                    for (int sI = 0; sI < 3; ++sI) v += red[c][sI][nt][lane];
                    const int t = t0 + nt * 16 + lrow;
#pragma unroll
                    for (int rr = 0; rr < 4; ++rr) {
                        const int f = ft * 16 + g * 4 + rr;
                        __builtin_nontemporal_store(v[rr] * inv[nt], ob + (size_t)f * T + t);
                    }
                }
            }
        }
    }
}

// ---------------------------------------------------------------------------
// Dense fallback (only if workspace is too small — slow but exact).
// ---------------------------------------------------------------------------
__global__ void unpool_dense_fallback(const float* __restrict__ features,
                                      const float* __restrict__ unroll,
                                      const float* __restrict__ occ,
                                      float* __restrict__ out) {
    const int b = blockIdx.z;
    const int f = blockIdx.y;
    const int t = blockIdx.x * 64 + threadIdx.x;
    if (t >= T) return;
    const float* frow = features + ((size_t)b * F + f) * E;
    const float* ubp = unroll + (size_t)b * E * T;
    float acc = 0.0f;
    for (int e = 0; e < E; ++e) acc += frow[e] * ubp[(size_t)e * T + t];
    out[((size_t)b * F + f) * T + t] = acc / occ[b * T + t];
}

extern "C" void kernel_launch(void* const* d_in, const int* in_sizes, int n_in,
                              void* d_out, int out_size, void* d_ws, size_t ws_size,
                              hipStream_t stream) {
    const float* features = (const float*)d_in[0];   // (B,F,E) fp32
    const float* unroll   = (const float*)d_in[1];   // (B,E,T) fp32 (binary)
    const float* occ      = (const float*)d_in[2];   // (B,T)   fp32
    float* out = (float*)d_out;                      // (B,F,T) fp32

    const size_t afrag_bytes = (size_t)B * NKT * 8 * 512 * sizeof(unsigned short); // ~3.1 MB
    if (ws_size < afrag_bytes) {
        dim3 g((T + 63) / 64, F, B);
        unpool_dense_fallback<<<g, 64, 0, stream>>>(features, unroll, occ, out);
        return;
    }

    unsigned short* afrag = (unsigned short*)d_ws;

    const int nthr = B * NKT * 8 * 64;  // 192512
    build_afrag<<<(nthr + 255) / 256, 256, 0, stream>>>(features, afrag);

    unpool_mfma_ws<<<dim3(NTT, B), 256, 0, stream>>>(unroll, afrag, occ, out);
}